// Round 1
// baseline (185.448 us; speedup 1.0000x reference)
//
#include <hip/hip_runtime.h>
#include <math.h>

#define BV 4
#define NV 1024
#define IND 128
#define OUTD 128
#define NH 8
#define DD 16

// ---------------- kernel 1: xt = x @ W ; src/dst per-head dots ----------------
__global__ __launch_bounds__(128) void k1_proj(
    const float* __restrict__ x, const float* __restrict__ W,
    const float* __restrict__ a, float* __restrict__ xt,
    float* __restrict__ src, float* __restrict__ dst)
{
    const int row = blockIdx.x;      // b*N + n  (0..4095)
    const int c = threadIdx.x;       // 0..127 output channel
    __shared__ float xrow[IND];
    xrow[c] = x[(size_t)row * IND + c];
    __syncthreads();

    float acc = 0.f;
    #pragma unroll 8
    for (int k = 0; k < IND; ++k)
        acc = fmaf(xrow[k], W[k * OUTD + c], acc);
    xt[(size_t)row * OUTD + c] = acc;

    // per-head reductions: src = xt . a[0:16], dst = xt . a[16:32]
    const int d = c & 15;
    float s = acc * a[d];
    float t = acc * a[DD + d];
    #pragma unroll
    for (int off = 8; off >= 1; off >>= 1) {
        s += __shfl_xor(s, off, 16);
        t += __shfl_xor(t, off, 16);
    }
    if (d == 0) {
        const int h = c >> 4;  // 0..7
        src[(size_t)row * NH + h] = s;
        dst[(size_t)row * NH + h] = t;
    }
}

// ---------------- kernel 2: per (b,i) masked softmax + weighted sum ----------
__global__ __launch_bounds__(256) void k2_gat(
    const float* __restrict__ adj, const float* __restrict__ xt,
    const float* __restrict__ src, const float* __restrict__ dst,
    float* __restrict__ out)
{
    const int wg = blockIdx.x;       // b*N + i
    const int b = wg >> 10;
    const int i = wg & (NV - 1);
    const int tid = threadIdx.x;

    __shared__ float w_lds[NV][NH];   // 32 KB: holds dst[b] first, then weights
    __shared__ float adj_lds[NV];     // 4 KB
    __shared__ float red[4 * NH];
    __shared__ float mx_s[NH], den_s[NH];
    __shared__ float part[128];

    const float* adjrow = adj + ((size_t)b * NV + i) * NV;
    for (int j = tid; j < NV; j += 256) adj_lds[j] = adjrow[j];

    const float* dstb = dst + (size_t)b * NV * NH;
    float* w_flat = &w_lds[0][0];
    for (int t = tid; t < NV * NH; t += 256) w_flat[t] = dstb[t];

    float srcv[NH];
    #pragma unroll
    for (int h = 0; h < NH; ++h) srcv[h] = src[((size_t)b * NV + i) * NH + h];
    __syncthreads();

    // ---- phase A: per-head max over masked j ----
    float mx[NH];
    #pragma unroll
    for (int h = 0; h < NH; ++h) mx[h] = -INFINITY;
    for (int j = tid; j < NV; j += 256) {
        const bool m = (adj_lds[j] > 0.f) || (j == i);
        if (m) {
            #pragma unroll
            for (int h = 0; h < NH; ++h) {
                float e = srcv[h] + w_lds[j][h];
                e = (e > 0.f) ? e : 0.2f * e;
                mx[h] = fmaxf(mx[h], e);
            }
        }
    }
    #pragma unroll
    for (int h = 0; h < NH; ++h)
        #pragma unroll
        for (int off = 32; off >= 1; off >>= 1)
            mx[h] = fmaxf(mx[h], __shfl_xor(mx[h], off, 64));
    const int wave = tid >> 6, lane = tid & 63;
    if (lane == 0) {
        #pragma unroll
        for (int h = 0; h < NH; ++h) red[wave * NH + h] = mx[h];
    }
    __syncthreads();
    if (tid < NH)
        mx_s[tid] = fmaxf(fmaxf(red[tid], red[NH + tid]),
                          fmaxf(red[2 * NH + tid], red[3 * NH + tid]));
    __syncthreads();
    #pragma unroll
    for (int h = 0; h < NH; ++h) mx[h] = mx_s[h];

    // ---- phase B: weights (overwrite dst slots) + denominator ----
    float den[NH];
    #pragma unroll
    for (int h = 0; h < NH; ++h) den[h] = 0.f;
    for (int j = tid; j < NV; j += 256) {
        const bool m = (adj_lds[j] > 0.f) || (j == i);
        #pragma unroll
        for (int h = 0; h < NH; ++h) {
            float e = srcv[h] + w_lds[j][h];
            e = (e > 0.f) ? e : 0.2f * e;
            float wv = m ? __expf(e - mx[h]) : 1.0f;
            w_lds[j][h] = wv;
            den[h] += wv;
        }
    }
    #pragma unroll
    for (int h = 0; h < NH; ++h)
        #pragma unroll
        for (int off = 32; off >= 1; off >>= 1)
            den[h] += __shfl_xor(den[h], off, 64);
    if (lane == 0) {
        #pragma unroll
        for (int h = 0; h < NH; ++h) red[wave * NH + h] = den[h];
    }
    __syncthreads();
    if (tid < NH)
        den_s[tid] = (red[tid] + red[NH + tid]) + (red[2 * NH + tid] + red[3 * NH + tid]);
    __syncthreads();  // also makes all w_lds writes visible

    // ---- phase C: out[c] = relu( sum_j w[j][h]*xt[b,j,c] / den[h] ) ----
    const int c = tid & 127;
    const int half = tid >> 7;
    const int h = c >> 4;
    const float* xtb = xt + (size_t)b * NV * OUTD;
    float acc = 0.f;
    const int j0 = half * (NV / 2);
    #pragma unroll 1
    for (int j = j0; j < j0 + NV / 2; j += 4) {
        acc = fmaf(w_lds[j + 0][h], xtb[(size_t)(j + 0) * OUTD + c], acc);
        acc = fmaf(w_lds[j + 1][h], xtb[(size_t)(j + 1) * OUTD + c], acc);
        acc = fmaf(w_lds[j + 2][h], xtb[(size_t)(j + 2) * OUTD + c], acc);
        acc = fmaf(w_lds[j + 3][h], xtb[(size_t)(j + 3) * OUTD + c], acc);
    }
    if (half == 1) part[c] = acc;
    __syncthreads();
    if (half == 0) {
        const float num = acc + part[c];
        const float r = num / den_s[h];
        out[((size_t)b * NV + i) * OUTD + c] = (r > 0.f) ? r : 0.f;
    }
}

extern "C" void kernel_launch(void* const* d_in, const int* in_sizes, int n_in,
                              void* d_out, int out_size, void* d_ws, size_t ws_size,
                              hipStream_t stream)
{
    const float* x   = (const float*)d_in[0];
    const float* adj = (const float*)d_in[1];
    const float* W   = (const float*)d_in[2];
    const float* a   = (const float*)d_in[3];
    float* out = (float*)d_out;

    float* ws = (float*)d_ws;
    float* xt  = ws;                              // 4096*128
    float* src = xt + (size_t)BV * NV * OUTD;     // 4096*8
    float* dst = src + (size_t)BV * NV * NH;      // 4096*8

    k1_proj<<<BV * NV, 128, 0, stream>>>(x, W, a, xt, src, dst);
    k2_gat<<<BV * NV, 256, 0, stream>>>(adj, xt, src, dst, out);
}

// Round 2
// 100.403 us; speedup vs baseline: 1.8470x; 1.8470x over previous
//
#include <hip/hip_runtime.h>
#include <math.h>
#include <stdint.h>

#define BV 4
#define NV 1024
#define IND 128
#define OUTD 128
#define NH 8
#define DD 16
#define ITILE 8     // i rows per k2 block
#define JCHUNK 64   // xt rows staged per LDS chunk

// swap bit0 <-> bit3 of a 5-bit float4-slot index (involution) so that the
// 16 stride-2 slot reads per wave land 2-per-bank instead of 4-per-bank.
__device__ __forceinline__ int swz(int s) {
    return (s & 22) | ((s & 1) << 3) | ((s >> 3) & 1);
}

// ---------------- kernel 0: mask bitwords (diagonal forced in) --------------
__global__ __launch_bounds__(256) void k0_bits(
    const float* __restrict__ adj, uint32_t* __restrict__ bits)
{
    const int row = blockIdx.x;          // b*NV + i
    const int i = row & (NV - 1);
    const int wave = threadIdx.x >> 6, lane = threadIdx.x & 63;
    const float* arow = adj + (size_t)row * NV;
    #pragma unroll
    for (int r = 0; r < 4; ++r) {
        const int j = (r * 4 + wave) * 64 + lane;
        const bool m = (arow[j] > 0.f) || (j == i);
        const unsigned long long bal = __ballot(m);
        if (lane == 0) {
            bits[(size_t)row * 32 + (r * 4 + wave) * 2]     = (uint32_t)bal;
            bits[(size_t)row * 32 + (r * 4 + wave) * 2 + 1] = (uint32_t)(bal >> 32);
        }
    }
}

// ---------------- kernel 1: xt = x @ W ; src/dst per-head dots ----------------
__global__ __launch_bounds__(128) void k1_proj(
    const float* __restrict__ x, const float* __restrict__ W,
    const float* __restrict__ a, float* __restrict__ xt,
    float* __restrict__ src, float* __restrict__ dst)
{
    const int row = blockIdx.x;      // b*N + n
    const int c = threadIdx.x;       // 0..127
    __shared__ float xrow[IND];
    xrow[c] = x[(size_t)row * IND + c];
    __syncthreads();

    float acc = 0.f;
    #pragma unroll 8
    for (int k = 0; k < IND; ++k)
        acc = fmaf(xrow[k], W[k * OUTD + c], acc);
    xt[(size_t)row * OUTD + c] = acc;

    const int d = c & 15;
    float s = acc * a[d];
    float t = acc * a[DD + d];
    #pragma unroll
    for (int off = 8; off >= 1; off >>= 1) {
        s += __shfl_xor(s, off, 16);
        t += __shfl_xor(t, off, 16);
    }
    if (d == 0) {
        const int h = c >> 4;
        src[(size_t)row * NH + h] = s;
        dst[(size_t)row * NH + h] = t;
    }
}

// ---------------- kernel 2: per-thread (i,h,8d) fused softmax+aggregate -----
__global__ __launch_bounds__(128) void k2_gat(
    const uint32_t* __restrict__ bits, const float* __restrict__ xt,
    const float* __restrict__ src, const float* __restrict__ dst,
    float* __restrict__ out)
{
    // XCD-aware swizzle: 512 blocks, assume bid%8 -> XCD; give each XCD one b
    const int sid = blockIdx.x;
    const int xcd = sid & 7;
    const int slot = sid >> 3;                 // 0..63
    const int b = xcd >> 1;
    const int tile = ((xcd & 1) << 6) | slot;  // 0..127
    const int i0 = tile * ITILE;

    const int tid = threadIdx.x;               // 0..127
    const int il = tid >> 4;                   // 0..7  (i within tile)
    const int h = (tid >> 1) & 7;              // head
    const int half = tid & 1;                  // d-half
    const int i = i0 + il;
    const int dg = 2 * h + half;               // 0..15
    const int dbase = dg * 8;                  // first of 8 channels owned

    __shared__ float dst_lds[NV][NH];                  // 32 KB
    __shared__ float4 xt_lds[JCHUNK * (OUTD / 4)];     // 32 KB, swizzled slots
    __shared__ uint32_t bits_lds[ITILE][NV / 32];      // 1 KB

    // stage dst[b] (flat, coalesced) + mask bits for this tile
    {
        const float4* sp = (const float4*)(dst + (size_t)b * NV * NH);
        float4* dp = (float4*)&dst_lds[0][0];
        #pragma unroll
        for (int t = 0; t < (NV * NH / 4) / 128; ++t)
            dp[tid + t * 128] = sp[tid + t * 128];
        const uint32_t* bsrc = bits + ((size_t)b * NV + i0) * (NV / 32);
        uint32_t* bdst = &bits_lds[0][0];
        bdst[tid] = bsrc[tid];
        bdst[tid + 128] = bsrc[tid + 128];
    }
    const float srcv = src[((size_t)b * NV + i) * NH + h];
    __syncthreads();

    // ---- pass A: mx = lrelu(src + max_{masked j} dst[j][h]) (monotone lrelu)
    // each half-thread scans 512 j's; combine with one shfl.
    float dmax = -INFINITY;
    {
        const int w0 = half * 16;
        #pragma unroll 2
        for (int jw = 0; jw < 16; ++jw) {
            const uint32_t word = bits_lds[il][w0 + jw];
            const int jb0 = (w0 + jw) * 32;
            #pragma unroll 8
            for (int jb = 0; jb < 32; ++jb) {
                const float dv = dst_lds[jb0 + jb][h];
                dmax = ((word >> jb) & 1) ? fmaxf(dmax, dv) : dmax;
            }
        }
    }
    dmax = fmaxf(dmax, __shfl_xor(dmax, 1));
    const float e0 = srcv + dmax;
    const float mx = fmaxf(e0, 0.2f * e0);

    // ---- pass B: fused weights + denominator + weighted sum ----
    float acc0 = 0, acc1 = 0, acc2 = 0, acc3 = 0;
    float acc4 = 0, acc5 = 0, acc6 = 0, acc7 = 0;
    float den = 0.f;
    const int s1 = swz(2 * dg), s2 = swz(2 * dg + 1);

    for (int c0 = 0; c0 < NV; c0 += JCHUNK) {
        __syncthreads();   // previous chunk's reads complete
        {   // stage 64 rows of xt[b] into LDS with swizzled slot placement
            const float4* xsrc = (const float4*)(xt + ((size_t)b * NV + c0) * OUTD);
            #pragma unroll
            for (int t = 0; t < 16; ++t) {
                const int idx = tid + t * 128;
                const int row = idx >> 5, sl = idx & 31;
                xt_lds[row * 32 + swz(sl)] = xsrc[idx];
            }
        }
        __syncthreads();

        #pragma unroll 2
        for (int wi = 0; wi < 2; ++wi) {
            const uint32_t word = bits_lds[il][(c0 >> 5) + wi];
            #pragma unroll 8
            for (int jb = 0; jb < 32; ++jb) {
                const int jj = wi * 32 + jb;
                const float dv = dst_lds[c0 + jj][h];
                float e = srcv + dv;
                e = fmaxf(e, 0.2f * e);
                const float w = ((word >> jb) & 1) ? __expf(e - mx) : 1.0f;
                den += w;
                const float4 xa = xt_lds[jj * 32 + s1];
                const float4 xb = xt_lds[jj * 32 + s2];
                acc0 = fmaf(w, xa.x, acc0);
                acc1 = fmaf(w, xa.y, acc1);
                acc2 = fmaf(w, xa.z, acc2);
                acc3 = fmaf(w, xa.w, acc3);
                acc4 = fmaf(w, xb.x, acc4);
                acc5 = fmaf(w, xb.y, acc5);
                acc6 = fmaf(w, xb.z, acc6);
                acc7 = fmaf(w, xb.w, acc7);
            }
        }
    }

    const float r = 1.0f / den;
    float4 o1, o2;
    o1.x = fmaxf(acc0 * r, 0.f);
    o1.y = fmaxf(acc1 * r, 0.f);
    o1.z = fmaxf(acc2 * r, 0.f);
    o1.w = fmaxf(acc3 * r, 0.f);
    o2.x = fmaxf(acc4 * r, 0.f);
    o2.y = fmaxf(acc5 * r, 0.f);
    o2.z = fmaxf(acc6 * r, 0.f);
    o2.w = fmaxf(acc7 * r, 0.f);
    float* op = out + ((size_t)b * NV + i) * OUTD + dbase;
    *(float4*)op = o1;
    *(float4*)(op + 4) = o2;
}

extern "C" void kernel_launch(void* const* d_in, const int* in_sizes, int n_in,
                              void* d_out, int out_size, void* d_ws, size_t ws_size,
                              hipStream_t stream)
{
    const float* x   = (const float*)d_in[0];
    const float* adj = (const float*)d_in[1];
    const float* W   = (const float*)d_in[2];
    const float* a   = (const float*)d_in[3];
    float* out = (float*)d_out;

    float* ws = (float*)d_ws;
    float* xt  = ws;                               // 4*1024*128
    float* src = xt + (size_t)BV * NV * OUTD;      // 4*1024*8
    float* dst = src + (size_t)BV * NV * NH;       // 4*1024*8
    uint32_t* bits = (uint32_t*)(dst + (size_t)BV * NV * NH);  // 4*1024*32 words

    k0_bits<<<BV * NV, 256, 0, stream>>>(adj, bits);
    k1_proj<<<BV * NV, 128, 0, stream>>>(x, W, a, xt, src, dst);
    k2_gat<<<512, 128, 0, stream>>>(bits, xt, src, dst, out);
}

// Round 3
// 48.574 us; speedup vs baseline: 3.8179x; 2.0670x over previous
//
#include <hip/hip_runtime.h>
#include <hip/hip_bf16.h>
#include <math.h>
#include <stdint.h>

#define BV 4
#define NV 1024
#define IND 128
#define OUTD 128
#define NH 8
#define DD 16
#define LOG2E 1.4426950408889634f

typedef __attribute__((ext_vector_type(8))) short bf16x8;
typedef __attribute__((ext_vector_type(4))) float f32x4;

__device__ __forceinline__ ushort bf16rne(float f) {
    uint32_t u = __float_as_uint(f);
    u += 0x7fff + ((u >> 16) & 1);
    return (ushort)(u >> 16);
}

// ---------------- kernel 0: mask bitwords (diagonal forced in) --------------
__global__ __launch_bounds__(256) void k0_bits(
    const float* __restrict__ adj, uint32_t* __restrict__ bits)
{
    const int row = blockIdx.x;          // b*NV + i
    const int i = row & (NV - 1);
    const int wave = threadIdx.x >> 6, lane = threadIdx.x & 63;
    const float* arow = adj + (size_t)row * NV;
    #pragma unroll
    for (int r = 0; r < 4; ++r) {
        const int j = (r * 4 + wave) * 64 + lane;
        const bool m = (arow[j] > 0.f) || (j == i);
        const unsigned long long bal = __ballot(m);
        if (lane == 0) {
            bits[(size_t)row * 32 + (r * 4 + wave) * 2]     = (uint32_t)bal;
            bits[(size_t)row * 32 + (r * 4 + wave) * 2 + 1] = (uint32_t)(bal >> 32);
        }
    }
}

// ------- kernel 1: xt = x@W ; src/dst per-head dots (pre-scaled by log2e) ----
__global__ __launch_bounds__(128) void k1_proj(
    const float* __restrict__ x, const float* __restrict__ W,
    const float* __restrict__ a, float* __restrict__ xt,
    float* __restrict__ src, float* __restrict__ dst_t)
{
    const int row = blockIdx.x;      // b*NV + n
    const int b = row >> 10, n = row & (NV - 1);
    const int c = threadIdx.x;       // 0..127
    __shared__ float xrow[IND];
    xrow[c] = x[(size_t)row * IND + c];
    __syncthreads();

    float acc = 0.f;
    #pragma unroll 8
    for (int k = 0; k < IND; ++k)
        acc = fmaf(xrow[k], W[k * OUTD + c], acc);
    xt[(size_t)row * OUTD + c] = acc;

    const int d = c & 15;
    float s = acc * a[d];
    float t = acc * a[DD + d];
    #pragma unroll
    for (int off = 8; off >= 1; off >>= 1) {
        s += __shfl_xor(s, off, 16);
        t += __shfl_xor(t, off, 16);
    }
    if (d == 0) {
        const int h = c >> 4;
        src[(size_t)row * NH + h] = s * LOG2E;
        dst_t[((size_t)(b * NH + h)) * NV + n] = t * LOG2E;
    }
}

// ------- kernel 1c: transpose xt -> bf16 hi/lo in [b][h][d][j] layout --------
__global__ __launch_bounds__(256) void k1c_tr(
    const float* __restrict__ xt, ushort* __restrict__ xhi, ushort* __restrict__ xlo)
{
    const int bid = blockIdx.x;          // 4*8*8 = 256 blocks
    const int jt = bid & 7, bh = bid >> 3;   // bh = b*8+h
    const int b = bh >> 3, h = bh & 7;
    const int tid = threadIdx.x;
    __shared__ float tile[128 * 20];     // pad 20 words/row

    #pragma unroll
    for (int k = 0; k < 2; ++k) {
        const int idx = tid + k * 256;   // 512 float4
        const int j = idx >> 2, ch = idx & 3;
        const float4 v = *(const float4*)&xt[((size_t)(b * NV) + jt * 128 + j) * OUTD + h * 16 + ch * 4];
        *(float4*)&tile[j * 20 + ch * 4] = v;
    }
    __syncthreads();

    const int d = tid & 15, oct = tid >> 4;   // oct 0..15 -> j-octet
    uint32_t ph[4], pl[4];
    #pragma unroll
    for (int p = 0; p < 4; ++p) {
        const float v0 = tile[(oct * 8 + 2 * p) * 20 + d];
        const float v1 = tile[(oct * 8 + 2 * p + 1) * 20 + d];
        const ushort h0 = bf16rne(v0), h1 = bf16rne(v1);
        const float f0 = __uint_as_float(((uint32_t)h0) << 16);
        const float f1 = __uint_as_float(((uint32_t)h1) << 16);
        const ushort l0 = bf16rne(v0 - f0), l1 = bf16rne(v1 - f1);
        ph[p] = (uint32_t)h0 | ((uint32_t)h1 << 16);
        pl[p] = (uint32_t)l0 | ((uint32_t)l1 << 16);
    }
    const size_t base = ((size_t)bh * 16 + d) * NV + jt * 128 + oct * 8;
    uint4 uh = {ph[0], ph[1], ph[2], ph[3]};
    uint4 ul = {pl[0], pl[1], pl[2], pl[3]};
    *(uint4*)&xhi[base] = uh;
    *(uint4*)&xlo[base] = ul;
}

// ------------- kernel 2: flash-style masked softmax + MFMA aggregation ------
__global__ __launch_bounds__(256) void k2_gat(
    const uint32_t* __restrict__ bits, const ushort* __restrict__ xhi,
    const ushort* __restrict__ xlo, const float* __restrict__ dst_t,
    const float* __restrict__ src, float* __restrict__ out)
{
    // grid 512; XCD-swizzle: blocks on one XCD share (b,h)
    const int bid = blockIdx.x;
    const int xcd = bid & 7, sl = bid >> 3;  // sl 0..63
    const int bh = xcd * 4 + (sl >> 4);      // 0..31
    const int it = sl & 15;
    const int b = bh >> 3, h = bh & 7;
    const int i0 = it * 64;

    const int tid = threadIdx.x;
    const int wv = tid >> 6, lane = tid & 63;
    const int g = lane >> 4, r16 = lane & 15;

    __shared__ ushort ahi[16 * 1032];     // xt hi, [d][j] padded
    __shared__ ushort alo[16 * 1032];     // xt lo
    __shared__ float dstl[NV];            // dst_t[bh][*]
    __shared__ uint32_t bl[64 * 33];      // mask bits, padded rows

    // ---- stage ----
    const uint4* ghi = (const uint4*)(xhi + (size_t)bh * 16 * NV);
    const uint4* glo = (const uint4*)(xlo + (size_t)bh * 16 * NV);
    #pragma unroll
    for (int k = 0; k < 8; ++k) {
        const int idx = tid + k * 256;    // 2048 uint4
        const int d = idx >> 7, jo = idx & 127;
        *(uint4*)&ahi[d * 1032 + jo * 8] = ghi[idx];
        *(uint4*)&alo[d * 1032 + jo * 8] = glo[idx];
    }
    {
        const float4* gd = (const float4*)(dst_t + (size_t)bh * NV);
        *(float4*)&dstl[tid * 4] = gd[tid];
    }
    #pragma unroll
    for (int k = 0; k < 8; ++k) {
        const int idx = tid + k * 256;    // 2048 words
        const int rr = idx >> 5, w = idx & 31;
        bl[rr * 33 + w] = bits[((size_t)(b * NV) + i0 + rr) * 32 + w];
    }
    const int myrow = wv * 16 + r16;      // A-side row within tile (0..63)
    const float srcv = src[((size_t)(b * NV) + i0 + myrow) * NH + h];
    __syncthreads();

    // ---- prepass: masked max of dst over this lane's j-range, reduce ----
    float dmax = -INFINITY;
    #pragma unroll 4
    for (int st = 0; st < 32; ++st) {
        const int jj = g * 256 + st * 8;
        const uint32_t word = bl[myrow * 33 + (jj >> 5)];
        const uint32_t bb = (word >> (jj & 31)) & 0xffu;
        const float4 v0 = *(const float4*)&dstl[jj];
        const float4 v1 = *(const float4*)&dstl[jj + 4];
        if (bb & 0x01u) dmax = fmaxf(dmax, v0.x);
        if (bb & 0x02u) dmax = fmaxf(dmax, v0.y);
        if (bb & 0x04u) dmax = fmaxf(dmax, v0.z);
        if (bb & 0x08u) dmax = fmaxf(dmax, v0.w);
        if (bb & 0x10u) dmax = fmaxf(dmax, v1.x);
        if (bb & 0x20u) dmax = fmaxf(dmax, v1.y);
        if (bb & 0x40u) dmax = fmaxf(dmax, v1.z);
        if (bb & 0x80u) dmax = fmaxf(dmax, v1.w);
    }
    dmax = fmaxf(dmax, __shfl_xor(dmax, 16));
    dmax = fmaxf(dmax, __shfl_xor(dmax, 32));
    const float S = srcv + dmax;
    const float mx = fmaxf(S, 0.2f * S);   // exact same op chain as per-element

    // ---- main K-loop: build alpha fragment, 2 chained MFMAs (hi+lo) ----
    f32x4 acc = {0.f, 0.f, 0.f, 0.f};
    float den = 0.f;
    const int shift = g * 8;
    float wt[8];
    #pragma unroll 2
    for (int s = 0; s < 32; ++s) {
        const int js = s * 32 + shift;
        const uint32_t bb = (bl[myrow * 33 + s] >> shift) & 0xffu;
        const float4 d0 = *(const float4*)&dstl[js];
        const float4 d1 = *(const float4*)&dstl[js + 4];
        const float dv[8] = {d0.x, d0.y, d0.z, d0.w, d1.x, d1.y, d1.z, d1.w};
        #pragma unroll
        for (int t = 0; t < 8; ++t) {
            const float sum = srcv + dv[t];
            const float el = fmaxf(sum, 0.2f * sum);
            const float ar = (bb & (1u << t)) ? (el - mx) : 0.0f;
            wt[t] = exp2f(ar);
            den += wt[t];
        }
        union { __hip_bfloat162 h2[4]; bf16x8 v; } af;
        af.h2[0] = __float22bfloat162_rn(make_float2(wt[0], wt[1]));
        af.h2[1] = __float22bfloat162_rn(make_float2(wt[2], wt[3]));
        af.h2[2] = __float22bfloat162_rn(make_float2(wt[4], wt[5]));
        af.h2[3] = __float22bfloat162_rn(make_float2(wt[6], wt[7]));
        const bf16x8 vh = *(const bf16x8*)&ahi[r16 * 1032 + js];
        const bf16x8 vl = *(const bf16x8*)&alo[r16 * 1032 + js];
        acc = __builtin_amdgcn_mfma_f32_16x16x32_bf16(af.v, vh, acc, 0, 0, 0);
        acc = __builtin_amdgcn_mfma_f32_16x16x32_bf16(af.v, vl, acc, 0, 0, 0);
    }

    // ---- epilogue: den reduce + normalize + relu + store ----
    den += __shfl_xor(den, 16);
    den += __shfl_xor(den, 32);          // valid for row r16 at every lane
    #pragma unroll
    for (int q = 0; q < 4; ++q) {
        const int orow = g * 4 + q;      // D row for this lane
        const float dq = __shfl(den, orow);   // lane 'orow' has r16 == orow
        float rv = acc[q] / dq;
        rv = fmaxf(rv, 0.f);
        out[((size_t)(b * NV) + i0 + wv * 16 + orow) * OUTD + h * 16 + r16] = rv;
    }
}

extern "C" void kernel_launch(void* const* d_in, const int* in_sizes, int n_in,
                              void* d_out, int out_size, void* d_ws, size_t ws_size,
                              hipStream_t stream)
{
    const float* x   = (const float*)d_in[0];
    const float* adj = (const float*)d_in[1];
    const float* W   = (const float*)d_in[2];
    const float* a   = (const float*)d_in[3];
    float* out = (float*)d_out;

    char* ws = (char*)d_ws;
    float* xt      = (float*)ws;                                   // 4096*128 f  (2 MB)
    float* dst_t   = (float*)(ws + 2 * 1024 * 1024);               // 32768 f     (128 KB)
    float* src     = (float*)(ws + 2 * 1024 * 1024 + 128 * 1024);  // 32768 f     (128 KB)
    uint32_t* bits = (uint32_t*)(ws + 2 * 1024 * 1024 + 256 * 1024);   // 131072 w (512 KB)
    ushort* xhi    = (ushort*)(ws + 2 * 1024 * 1024 + 768 * 1024);     // 524288 u16 (1 MB)
    ushort* xlo    = (ushort*)(ws + 3 * 1024 * 1024 + 768 * 1024);     // 524288 u16 (1 MB)

    k0_bits<<<BV * NV, 256, 0, stream>>>(adj, bits);
    k1_proj<<<BV * NV, 128, 0, stream>>>(x, W, a, xt, src, dst_t);
    k1c_tr<<<256, 256, 0, stream>>>(xt, xhi, xlo);
    k2_gat<<<512, 256, 0, stream>>>(bits, xhi, xlo, dst_t, src, out);
}

// Round 4
// 41.434 us; speedup vs baseline: 4.4757x; 1.1723x over previous
//
#include <hip/hip_runtime.h>
#include <hip/hip_bf16.h>
#include <math.h>
#include <stdint.h>

#define BV 4
#define NV 1024
#define IND 128
#define OUTD 128
#define NH 8
#define DD 16
#define LOG2E 1.4426950408889634f

typedef __attribute__((ext_vector_type(8))) short bf16x8;
typedef __attribute__((ext_vector_type(4))) float f32x4;

__device__ __forceinline__ ushort bf16rne(float f) {
    uint32_t u = __float_as_uint(f);
    u += 0x7fff + ((u >> 16) & 1);
    return (ushort)(u >> 16);
}

// ---------------- kernel 0: mask bitwords (diagonal forced in) --------------
__global__ __launch_bounds__(256) void k0_bits(
    const float* __restrict__ adj, uint32_t* __restrict__ bits)
{
    const int row = blockIdx.x;          // b*NV + i
    const int i = row & (NV - 1);
    const int wave = threadIdx.x >> 6, lane = threadIdx.x & 63;
    const float* arow = adj + (size_t)row * NV;
    #pragma unroll
    for (int r = 0; r < 4; ++r) {
        const int j = (r * 4 + wave) * 64 + lane;
        const bool m = (arow[j] > 0.f) || (j == i);
        const unsigned long long bal = __ballot(m);
        if (lane == 0) {
            bits[(size_t)row * 32 + (r * 4 + wave) * 2]     = (uint32_t)bal;
            bits[(size_t)row * 32 + (r * 4 + wave) * 2 + 1] = (uint32_t)(bal >> 32);
        }
    }
}

// ---------------- kernel 1: pure GEMM xt = x @ W (8 rows/block) -------------
__global__ __launch_bounds__(256) void k1_proj(
    const float* __restrict__ x, const float* __restrict__ W,
    float* __restrict__ xt)
{
    const int r0 = blockIdx.x * 8;
    const int tid = threadIdx.x;
    const int c = tid & 127, hf = tid >> 7;   // hf: row half (4 rows each)

    __shared__ float xs[8][132];
    {
        const int row = tid >> 5, c4 = tid & 31;
        *(float4*)&xs[row][c4 * 4] = *(const float4*)&x[((size_t)(r0 + row)) * IND + c4 * 4];
    }
    __syncthreads();

    float acc0 = 0.f, acc1 = 0.f, acc2 = 0.f, acc3 = 0.f;
    const int rb = hf * 4;
    #pragma unroll 4
    for (int k4 = 0; k4 < IND; k4 += 4) {
        const float4 a0 = *(const float4*)&xs[rb + 0][k4];
        const float4 a1 = *(const float4*)&xs[rb + 1][k4];
        const float4 a2 = *(const float4*)&xs[rb + 2][k4];
        const float4 a3 = *(const float4*)&xs[rb + 3][k4];
        const float w0 = W[(k4 + 0) * OUTD + c];
        const float w1 = W[(k4 + 1) * OUTD + c];
        const float w2 = W[(k4 + 2) * OUTD + c];
        const float w3 = W[(k4 + 3) * OUTD + c];
        acc0 = fmaf(a0.x, w0, fmaf(a0.y, w1, fmaf(a0.z, w2, fmaf(a0.w, w3, acc0))));
        acc1 = fmaf(a1.x, w0, fmaf(a1.y, w1, fmaf(a1.z, w2, fmaf(a1.w, w3, acc1))));
        acc2 = fmaf(a2.x, w0, fmaf(a2.y, w1, fmaf(a2.z, w2, fmaf(a2.w, w3, acc2))));
        acc3 = fmaf(a3.x, w0, fmaf(a3.y, w1, fmaf(a3.z, w2, fmaf(a3.w, w3, acc3))));
    }
    xt[((size_t)(r0 + rb + 0)) * OUTD + c] = acc0;
    xt[((size_t)(r0 + rb + 1)) * OUTD + c] = acc1;
    xt[((size_t)(r0 + rb + 2)) * OUTD + c] = acc2;
    xt[((size_t)(r0 + rb + 3)) * OUTD + c] = acc3;
}

// ------- kernel 1c: transpose xt -> bf16 hi/lo [bh][d][j] + src/dst dots ----
__global__ __launch_bounds__(256) void k1c_tr(
    const float* __restrict__ xt, const float* __restrict__ a,
    ushort* __restrict__ xhi, ushort* __restrict__ xlo,
    float* __restrict__ src, float* __restrict__ dst_t)
{
    const int bid = blockIdx.x;          // 256 blocks
    const int jt = bid & 7, bh = bid >> 3;   // bh = b*8+h
    const int b = bh >> 3, h = bh & 7;
    const int tid = threadIdx.x;
    __shared__ float tile[128 * 20];     // [j][d], pad 20

    #pragma unroll
    for (int k = 0; k < 2; ++k) {
        const int idx = tid + k * 256;   // 512 float4
        const int j = idx >> 2, ch = idx & 3;
        const float4 v = *(const float4*)&xt[((size_t)(b * NV) + jt * 128 + j) * OUTD + h * 16 + ch * 4];
        *(float4*)&tile[j * 20 + ch * 4] = v;
    }
    __syncthreads();

    // transpose to bf16 hi/lo
    const int d = tid & 15, oct = tid >> 4;
    uint32_t ph[4], pl[4];
    #pragma unroll
    for (int p = 0; p < 4; ++p) {
        const float v0 = tile[(oct * 8 + 2 * p) * 20 + d];
        const float v1 = tile[(oct * 8 + 2 * p + 1) * 20 + d];
        const ushort h0 = bf16rne(v0), h1 = bf16rne(v1);
        const float f0 = __uint_as_float(((uint32_t)h0) << 16);
        const float f1 = __uint_as_float(((uint32_t)h1) << 16);
        const ushort l0 = bf16rne(v0 - f0), l1 = bf16rne(v1 - f1);
        ph[p] = (uint32_t)h0 | ((uint32_t)h1 << 16);
        pl[p] = (uint32_t)l0 | ((uint32_t)l1 << 16);
    }
    const size_t base = ((size_t)bh * 16 + d) * NV + jt * 128 + oct * 8;
    uint4 uh = {ph[0], ph[1], ph[2], ph[3]};
    uint4 ul = {pl[0], pl[1], pl[2], pl[3]};
    *(uint4*)&xhi[base] = uh;
    *(uint4*)&xlo[base] = ul;

    // fused src/dst per-head dots (pre-scaled by log2e)
    const int j = tid >> 1, p = tid & 1;
    float s = 0.f, t = 0.f;
    #pragma unroll
    for (int e = 0; e < 8; ++e) {
        const float v = tile[j * 20 + p * 8 + e];
        s = fmaf(v, a[p * 8 + e], s);
        t = fmaf(v, a[DD + p * 8 + e], t);
    }
    s += __shfl_xor(s, 1);
    t += __shfl_xor(t, 1);
    if (p == 0) {
        const int grow = b * NV + jt * 128 + j;
        src[(size_t)grow * NH + h] = s * LOG2E;
        dst_t[(size_t)bh * NV + jt * 128 + j] = t * LOG2E;
    }
}

// ------------- kernel 2: flash-style masked softmax + MFMA (j-split) --------
__global__ __launch_bounds__(512, 4) void k2_gat(
    const uint32_t* __restrict__ bits, const ushort* __restrict__ xhi,
    const ushort* __restrict__ xlo, const float* __restrict__ dst_t,
    const float* __restrict__ src, float* __restrict__ out)
{
    // grid 512; blocks on one XCD share (b,h)
    const int bid = blockIdx.x;
    const int xcd = bid & 7, sl = bid >> 3;  // sl 0..63
    const int bh = xcd * 4 + (sl >> 4);      // 0..31
    const int it = sl & 15;
    const int b = bh >> 3, h = bh & 7;
    const int i0 = it * 64;

    const int tid = threadIdx.x;
    const int wv = tid >> 6, lane = tid & 63;
    const int g = lane >> 4, r16 = lane & 15;
    const int rg = wv & 3;                   // row group (16 rows)
    const int jh = wv >> 2;                  // j half (512 each)

    __shared__ ushort ahi[16 * 1032];        // [d][j] padded
    __shared__ ushort alo[16 * 1032];
    __shared__ float dstl[NV];
    __shared__ uint32_t bl[64 * 33];         // mask bits; aliased as red buf later
    __shared__ float mxx[2][64];

    // ---- stage ----
    const uint4* ghi = (const uint4*)(xhi + (size_t)bh * 16 * NV);
    const uint4* glo = (const uint4*)(xlo + (size_t)bh * 16 * NV);
    #pragma unroll
    for (int k = 0; k < 4; ++k) {
        const int idx = tid + k * 512;       // 2048 uint4
        const int d = idx >> 7, jo = idx & 127;
        *(uint4*)&ahi[d * 1032 + jo * 8] = ghi[idx];
        *(uint4*)&alo[d * 1032 + jo * 8] = glo[idx];
    }
    if (tid < 256) {
        const float4* gd = (const float4*)(dst_t + (size_t)bh * NV);
        *(float4*)&dstl[tid * 4] = gd[tid];
    }
    #pragma unroll
    for (int k = 0; k < 4; ++k) {
        const int idx = tid + k * 512;       // 2048 words
        const int rr = idx >> 5, w = idx & 31;
        bl[rr * 33 + w] = bits[((size_t)(b * NV) + i0 + rr) * 32 + w];
    }
    const int myrow = rg * 16 + r16;
    const float srcv = src[((size_t)(b * NV) + i0 + myrow) * NH + h];
    __syncthreads();

    // ---- prepass: masked max of dst over this wave's j-half ----
    float dmax = -INFINITY;
    #pragma unroll 4
    for (int st = 0; st < 16; ++st) {
        const int jj = jh * 512 + g * 128 + st * 8;
        const uint32_t word = bl[myrow * 33 + (jj >> 5)];
        const uint32_t bb = (word >> (jj & 31)) & 0xffu;
        const float4 v0 = *(const float4*)&dstl[jj];
        const float4 v1 = *(const float4*)&dstl[jj + 4];
        if (bb & 0x01u) dmax = fmaxf(dmax, v0.x);
        if (bb & 0x02u) dmax = fmaxf(dmax, v0.y);
        if (bb & 0x04u) dmax = fmaxf(dmax, v0.z);
        if (bb & 0x08u) dmax = fmaxf(dmax, v0.w);
        if (bb & 0x10u) dmax = fmaxf(dmax, v1.x);
        if (bb & 0x20u) dmax = fmaxf(dmax, v1.y);
        if (bb & 0x40u) dmax = fmaxf(dmax, v1.z);
        if (bb & 0x80u) dmax = fmaxf(dmax, v1.w);
    }
    dmax = fmaxf(dmax, __shfl_xor(dmax, 16));
    dmax = fmaxf(dmax, __shfl_xor(dmax, 32));
    if (g == 0) mxx[jh][myrow] = dmax;       // one lane per (row, half)
    __syncthreads();
    {
        const float dall = fmaxf(mxx[0][myrow], mxx[1][myrow]);
        dmax = dall;
    }
    const float S = srcv + dmax;
    const float mx = fmaxf(S, 0.2f * S);     // same op chain as per-element

    // ---- main K-loop over this wave's j-half ----
    f32x4 acc = {0.f, 0.f, 0.f, 0.f};
    float den = 0.f;
    const int shift = g * 8;
    float wt[8];
    #pragma unroll 2
    for (int s = 0; s < 16; ++s) {
        const int sw = jh * 16 + s;          // bit-word index
        const int js = sw * 32 + shift;
        const uint32_t bb = (bl[myrow * 33 + sw] >> shift) & 0xffu;
        const float4 d0 = *(const float4*)&dstl[js];
        const float4 d1 = *(const float4*)&dstl[js + 4];
        const float dv[8] = {d0.x, d0.y, d0.z, d0.w, d1.x, d1.y, d1.z, d1.w};
        #pragma unroll
        for (int t = 0; t < 8; ++t) {
            const float sum = srcv + dv[t];
            const float el = fmaxf(sum, 0.2f * sum);
            const float ar = (bb & (1u << t)) ? (el - mx) : 0.0f;
            wt[t] = exp2f(ar);
            den += wt[t];
        }
        union { __hip_bfloat162 h2[4]; bf16x8 v; } af;
        af.h2[0] = __float22bfloat162_rn(make_float2(wt[0], wt[1]));
        af.h2[1] = __float22bfloat162_rn(make_float2(wt[2], wt[3]));
        af.h2[2] = __float22bfloat162_rn(make_float2(wt[4], wt[5]));
        af.h2[3] = __float22bfloat162_rn(make_float2(wt[6], wt[7]));
        const bf16x8 vh = *(const bf16x8*)&ahi[r16 * 1032 + js];
        const bf16x8 vl = *(const bf16x8*)&alo[r16 * 1032 + js];
        acc = __builtin_amdgcn_mfma_f32_16x16x32_bf16(af.v, vh, acc, 0, 0, 0);
        acc = __builtin_amdgcn_mfma_f32_16x16x32_bf16(af.v, vl, acc, 0, 0, 0);
    }
    __syncthreads();                          // bl dead from here; alias as red

    float* red_acc = (float*)bl;              // 4 waves * 64 lanes * 4 = 4 KB
    float* red_den = (float*)bl + 1024;       // 4 waves * 64 lanes   = 1 KB
    if (jh == 1) {
        const int w4 = rg;
        *(float4*)&red_acc[(w4 * 64 + lane) * 4] = *(float4*)&acc;
        red_den[w4 * 64 + lane] = den;
    }
    __syncthreads();

    if (jh == 0) {
        const float4 oa = *(const float4*)&red_acc[(rg * 64 + lane) * 4];
        acc[0] += oa.x; acc[1] += oa.y; acc[2] += oa.z; acc[3] += oa.w;
        den += red_den[rg * 64 + lane];
        den += __shfl_xor(den, 16);
        den += __shfl_xor(den, 32);           // full-row den at matching r16
        #pragma unroll
        for (int q = 0; q < 4; ++q) {
            const int orow = g * 4 + q;       // C row for this lane
            const float dq = __shfl(den, orow);
            float rv = acc[q] / dq;
            rv = fmaxf(rv, 0.f);
            out[((size_t)(b * NV) + i0 + rg * 16 + orow) * OUTD + h * 16 + r16] = rv;
        }
    }
}

extern "C" void kernel_launch(void* const* d_in, const int* in_sizes, int n_in,
                              void* d_out, int out_size, void* d_ws, size_t ws_size,
                              hipStream_t stream)
{
    const float* x   = (const float*)d_in[0];
    const float* adj = (const float*)d_in[1];
    const float* W   = (const float*)d_in[2];
    const float* a   = (const float*)d_in[3];
    float* out = (float*)d_out;

    char* ws = (char*)d_ws;
    float* xt      = (float*)ws;                                   // 2 MB
    float* dst_t   = (float*)(ws + 2 * 1024 * 1024);               // 128 KB
    float* src     = (float*)(ws + 2 * 1024 * 1024 + 128 * 1024);  // 128 KB
    uint32_t* bits = (uint32_t*)(ws + 2 * 1024 * 1024 + 256 * 1024);   // 512 KB
    ushort* xhi    = (ushort*)(ws + 2 * 1024 * 1024 + 768 * 1024);     // 1 MB
    ushort* xlo    = (ushort*)(ws + 3 * 1024 * 1024 + 768 * 1024);     // 1 MB

    k0_bits<<<BV * NV, 256, 0, stream>>>(adj, bits);
    k1_proj<<<512, 256, 0, stream>>>(x, W, xt);
    k1c_tr<<<256, 256, 0, stream>>>(xt, a, xhi, xlo, src, dst_t);
    k2_gat<<<512, 512, 0, stream>>>(bits, xhi, xlo, dst_t, src, out);
}